// Round 4
// baseline (85.135 us; speedup 1.0000x reference)
//
#include <hip/hip_runtime.h>

// BBoxTransform — two-phase, dedup + vectorized + nontemporal + fast-trans.
//
// pred_boxes.flat[f] = concat_row[r][c], r=f/N, c=f%N; concat rows 0..63:
// k=r/8 in {x1,x2=x1,x3=x4,x4,y1,y2=y4,y3=y1,y4}, batch b=r%8; rows>=64: 1.0.
// V holds the 4 distinct corner arrays: v in {0:x1,1:x4,2:y1,3:y4},
// layout V[(v*8+b)*N + c]; map k -> v: k<4 ? k>>1 : 2+(k&1).
//
// Phase 1: 4 boxes/thread; NONTEMPORAL float4 input loads (inputs are
// read-once -> don't pollute L3, whose dirty fill-lines writeback steals
// HBM BW inside our window); fast __expf/__sinf/__cosf.
// Phase 2: 3x float4 V read + CTR read (cached, L3-hot), NONTEMPORAL out
// stores (out is never read).

typedef float f4v __attribute__((ext_vector_type(4)));

__device__ __forceinline__ f4v nt_load4(const float* p) {
    return __builtin_nontemporal_load((const f4v*)p);
}
__device__ __forceinline__ void nt_store4(float* p, f4v v) {
    __builtin_nontemporal_store(v, (f4v*)p);
}

__global__ __launch_bounds__(256) void bbox_phase1(
    const float* __restrict__ boxes, const float* __restrict__ deltas,
    float* __restrict__ V, float4* __restrict__ CTR, int N, int total)
{
    int t = blockIdx.x * blockDim.x + threadIdx.x;
    int i0 = t * 4;
    if (i0 >= total) return;
    int b = i0 / N;
    int c = i0 - b * N;

    bool fast = (i0 + 3 < total) && (c + 3 < N);   // N%4==0 in practice
    if (fast) {
        f4v B[5], D[5];
#pragma unroll
        for (int q = 0; q < 5; ++q) {
            B[q] = nt_load4(boxes  + (size_t)i0 * 5 + q * 4);
            D[q] = nt_load4(deltas + (size_t)i0 * 5 + q * 4);
        }
        float bv[20], dv[20];
#pragma unroll
        for (int q = 0; q < 5; ++q)
#pragma unroll
            for (int l = 0; l < 4; ++l) {
                bv[q * 4 + l] = B[q][l];
                dv[q * 4 + l] = D[q][l];
            }

        float X1[4], X4[4], Y1[4], Y4[4];
        float4 ctr[4];
#pragma unroll
        for (int j = 0; j < 4; ++j) {
            float b0 = bv[j*5+0], b1 = bv[j*5+1], b2 = bv[j*5+2],
                  b3 = bv[j*5+3], b4 = bv[j*5+4];
            float d0 = dv[j*5+0], d1 = dv[j*5+1], d2 = dv[j*5+2],
                  d3 = dv[j*5+3], d4 = dv[j*5+4];
            float w  = b2 - b0, h = b3 - b1;
            float pcx = b0 + 0.5f * w + (d0 * 0.1f) * w;
            float pcy = b1 + 0.5f * h + (d1 * 0.1f) * h;
            float pw  = __expf(d2 * 0.2f) * w;
            float ph  = __expf(d3 * 0.2f) * h;
            X1[j] = pcx - 0.5f * pw;  X4[j] = pcx + 0.5f * pw;
            Y1[j] = pcy - 0.5f * ph;  Y4[j] = pcy + 0.5f * ph;
            float pal = atanf(d4) + b4;
            float sa = __sinf(pal), ca = __cosf(pal);
            ctr[j] = make_float4(pcx, pcy, ca, sa);
        }
        size_t rs = (size_t)N;
        *(f4v*)(V + (size_t)(0*8 + b) * rs + c) = (f4v){X1[0],X1[1],X1[2],X1[3]};
        *(f4v*)(V + (size_t)(1*8 + b) * rs + c) = (f4v){X4[0],X4[1],X4[2],X4[3]};
        *(f4v*)(V + (size_t)(2*8 + b) * rs + c) = (f4v){Y1[0],Y1[1],Y1[2],Y1[3]};
        *(f4v*)(V + (size_t)(3*8 + b) * rs + c) = (f4v){Y4[0],Y4[1],Y4[2],Y4[3]};
        CTR[i0+0] = ctr[0]; CTR[i0+1] = ctr[1];
        CTR[i0+2] = ctr[2]; CTR[i0+3] = ctr[3];
    } else {
#pragma unroll 1
        for (int j = 0; j < 4; ++j) {
            int i = i0 + j;
            if (i >= total) break;
            int bb = i / N, cc = i - bb * N;
            const float* bx = boxes  + (size_t)i * 5;
            const float* dl = deltas + (size_t)i * 5;
            float b0=bx[0],b1=bx[1],b2=bx[2],b3=bx[3],b4=bx[4];
            float d0=dl[0],d1=dl[1],d2=dl[2],d3=dl[3],d4=dl[4];
            float w = b2-b0, h = b3-b1;
            float pcx = b0 + 0.5f*w + (d0*0.1f)*w;
            float pcy = b1 + 0.5f*h + (d1*0.1f)*h;
            float pw = __expf(d2*0.2f)*w, ph = __expf(d3*0.2f)*h;
            size_t rs = (size_t)N;
            V[(size_t)(0*8+bb)*rs + cc] = pcx - 0.5f*pw;
            V[(size_t)(1*8+bb)*rs + cc] = pcx + 0.5f*pw;
            V[(size_t)(2*8+bb)*rs + cc] = pcy - 0.5f*ph;
            V[(size_t)(3*8+bb)*rs + cc] = pcy + 0.5f*ph;
            float pal = atanf(d4) + b4;
            float sa = __sinf(pal), ca = __cosf(pal);
            CTR[i] = make_float4(pcx, pcy, ca, sa);
        }
    }
}

__global__ __launch_bounds__(256) void bbox_phase2(
    const float* __restrict__ V, const float4* __restrict__ CTR,
    float* __restrict__ out, int N, int total)
{
    int idx = blockIdx.x * blockDim.x + threadIdx.x;
    if (idx >= total) return;

    float4 t4 = CTR[idx];
    float pcx = t4.x, pcy = t4.y, ca = t4.z, sa = t4.w;

    int f = idx * 12;                 // < 24e6, fits int
    int r = f / N;
    int c = f - r * N;

    float P[12];
    if (c + 11 < N && (c & 3) == 0) {         // window within one concat row
        if (r < 64) {
            int k = r >> 3, b = r & 7;
            int v = (k < 4) ? (k >> 1) : (2 + (k & 1));
            const float4* wp = (const float4*)(V + (size_t)(v*8 + b) * N + c);
            float4 a = wp[0], bb = wp[1], cc = wp[2];
            P[0]=a.x; P[1]=a.y; P[2]=a.z;  P[3]=a.w;
            P[4]=bb.x;P[5]=bb.y;P[6]=bb.z; P[7]=bb.w;
            P[8]=cc.x;P[9]=cc.y;P[10]=cc.z;P[11]=cc.w;
        } else {
#pragma unroll
            for (int t = 0; t < 12; ++t) P[t] = 1.0f;
        }
    } else {
#pragma unroll
        for (int t = 0; t < 12; ++t) {
            int ct = c + t, rt = r;
            if (ct >= N) { ct -= N; rt += 1; }
            if (rt >= 64) { P[t] = 1.0f; }
            else {
                int k = rt >> 3, b = rt & 7;
                int v = (k < 4) ? (k >> 1) : (2 + (k & 1));
                P[t] = V[(size_t)(v*8 + b) * N + ct];
            }
        }
    }

    float r0o[4], r1o[4];
#pragma unroll
    for (int j = 0; j < 4; ++j) {
        float p0 = P[j], p1 = P[4 + j], p2 = P[8 + j];
        float u0 = p0 - pcx * p2;     // Tinv @ P
        float u1 = p1 - pcy * p2;
        float v0 = ca * u0 - sa * u1; // R @ ...
        float v1 = sa * u0 + ca * u1;
        r0o[j] = v0 + pcx * p2;       // T @ ...
        r1o[j] = v1 + pcy * p2;
    }

    float* op = out + (size_t)idx * 8;
    nt_store4(op,     (f4v){r0o[0], r1o[0], r0o[1], r1o[1]});
    nt_store4(op + 4, (f4v){r0o[2], r1o[2], r0o[3], r1o[3]});
}

// ---- fallback (fused, no workspace) ----
__global__ __launch_bounds__(256) void bbox_fused_fallback(
    const float* __restrict__ boxes, const float* __restrict__ deltas,
    float* __restrict__ out, int N, int total)
{
    int idx = blockIdx.x * blockDim.x + threadIdx.x;
    if (idx >= total) return;
    int bp = idx / N;
    int n  = idx - bp * N;
    const float* bx = boxes  + (size_t)idx * 5;
    const float* dl = deltas + (size_t)idx * 5;
    float b0=bx[0],b1=bx[1],b2=bx[2],b3=bx[3],b4=bx[4];
    float d0=dl[0],d1=dl[1],d4=dl[4];
    float w=b2-b0, h=b3-b1;
    float pcx = b0+0.5f*w+(d0*0.1f)*w;
    float pcy = b1+0.5f*h+(d1*0.1f)*h;
    float pal = atanf(d4)+b4;
    float sa = __sinf(pal), ca = __cosf(pal);
    int m0 = n*12, q = m0/N, c0 = m0-q*N, r0 = bp*12+q;
    float P[12];
#pragma unroll
    for (int t = 0; t < 12; ++t) {
        int c = c0+t, r = r0;
        if (c >= N) { c -= N; r += 1; }
        float v;
        if (r >= 64) v = 1.0f;
        else {
            int k = r>>3, b = r&7;
            size_t base = ((size_t)b*N + c)*5;
            int a = (k<4)?0:1;
            float lo = boxes[base+a], hi = boxes[base+a+2];
            float dc = deltas[base+a], dd = deltas[base+a+2];
            float ww = hi-lo;
            float pc = lo+0.5f*ww+(dc*0.1f)*ww;
            float pwv = __expf(dd*0.2f)*ww;
            float s = ((0xAC>>k)&1)?0.5f:-0.5f;
            v = pc + s*pwv;
        }
        P[t] = v;
    }
    float r0o[4], r1o[4];
#pragma unroll
    for (int j = 0; j < 4; ++j) {
        float p0=P[j], p1=P[4+j], p2=P[8+j];
        float u0=p0-pcx*p2, u1=p1-pcy*p2;
        float v0=ca*u0-sa*u1, v1=sa*u0+ca*u1;
        r0o[j]=v0+pcx*p2; r1o[j]=v1+pcy*p2;
    }
    float4* op = (float4*)(out + (size_t)idx*8);
    op[0] = make_float4(r0o[0],r1o[0],r0o[1],r1o[1]);
    op[1] = make_float4(r0o[2],r1o[2],r0o[3],r1o[3]);
}

extern "C" void kernel_launch(void* const* d_in, const int* in_sizes, int n_in,
                              void* d_out, int out_size, void* d_ws, size_t ws_size,
                              hipStream_t stream) {
    const float* boxes  = (const float*)d_in[0];
    const float* deltas = (const float*)d_in[1];
    float* out = (float*)d_out;

    int total = in_sizes[0] / 5;     // B * N
    int N = total / 8;               // B == 8
    int threads = 256;

    size_t vBytes   = (size_t)32 * N * sizeof(float);     // 32 distinct rows
    size_t ctrBytes = (size_t)total * sizeof(float4);
    if (ws_size >= vBytes + ctrBytes) {
        float*  V   = (float*)d_ws;
        float4* CTR = (float4*)((char*)d_ws + vBytes);
        int t1 = (total + 3) / 4;
        int blocks1 = (t1 + threads - 1) / threads;
        int blocks2 = (total + threads - 1) / threads;
        bbox_phase1<<<blocks1, threads, 0, stream>>>(boxes, deltas, V, CTR, N, total);
        bbox_phase2<<<blocks2, threads, 0, stream>>>(V, CTR, out, N, total);
    } else {
        int blocks = (total + threads - 1) / threads;
        bbox_fused_fallback<<<blocks, threads, 0, stream>>>(boxes, deltas, out, N, total);
    }
}

// Round 5
// 51.512 us; speedup vs baseline: 1.6527x; 1.6527x over previous
//
#include <hip/hip_runtime.h>

// BBoxTransform — two-phase, dedup + fp16 intermediates (L3-friendly).
//
// pred_boxes.flat[f] = concat_row[r][c], r=f/N, c=f%N; concat rows 0..63:
// k=r/8 in {x1,x2=x1,x3=x4,x4,y1,y2=y4,y3=y1,y4}, batch b=r%8; rows>=64: 1.0.
// V16 holds the 4 distinct corner arrays in fp16: v in {0:x1,1:x4,2:y1,3:y4},
// layout V16[(v*8+b)*N + c]; map k -> v: k<4 ? k>>1 : 2+(k&1).
// CTR16[i] = 4 halfs (pcx,pcy,ca,sa).
//
// R4 lesson: NT loads/stores regressed badly — the harness's 256MiB poison
// fill keeps L3 dirty-full, so every HBM-bypassing access and every newly
// allocated line pays full HBM price. Strategy: minimize bytes, keep all
// traffic cacheable. fp16 intermediates halve the V/CTR round trip
// (96 MB -> 48 MB); precision budget ~0.05 << 0.4275 threshold.

typedef float    f4v __attribute__((ext_vector_type(4)));
typedef _Float16 h4v __attribute__((ext_vector_type(4)));
typedef _Float16 h8v __attribute__((ext_vector_type(8)));

__global__ __launch_bounds__(256) void bbox_phase1(
    const float* __restrict__ boxes, const float* __restrict__ deltas,
    _Float16* __restrict__ V, _Float16* __restrict__ CTR, int N, int total)
{
    int t = blockIdx.x * blockDim.x + threadIdx.x;
    int i0 = t * 4;
    if (i0 >= total) return;
    int b = i0 / N;
    int c = i0 - b * N;

    bool fast = (i0 + 3 < total) && (c + 3 < N) && ((c & 3) == 0) && ((N & 3) == 0);
    if (fast) {
        const f4v* bp = (const f4v*)(boxes  + (size_t)i0 * 5);
        const f4v* dp = (const f4v*)(deltas + (size_t)i0 * 5);
        float bv[20], dv[20];
        *(f4v*)&bv[0]  = bp[0]; *(f4v*)&bv[4]  = bp[1]; *(f4v*)&bv[8]  = bp[2];
        *(f4v*)&bv[12] = bp[3]; *(f4v*)&bv[16] = bp[4];
        *(f4v*)&dv[0]  = dp[0]; *(f4v*)&dv[4]  = dp[1]; *(f4v*)&dv[8]  = dp[2];
        *(f4v*)&dv[12] = dp[3]; *(f4v*)&dv[16] = dp[4];

        float X1[4], X4[4], Y1[4], Y4[4], PX[4], PY[4], CA[4], SA[4];
#pragma unroll
        for (int j = 0; j < 4; ++j) {
            float b0 = bv[j*5+0], b1 = bv[j*5+1], b2 = bv[j*5+2],
                  b3 = bv[j*5+3], b4 = bv[j*5+4];
            float d0 = dv[j*5+0], d1 = dv[j*5+1], d2 = dv[j*5+2],
                  d3 = dv[j*5+3], d4 = dv[j*5+4];
            float w  = b2 - b0, h = b3 - b1;
            float pcx = b0 + 0.5f * w + (d0 * 0.1f) * w;
            float pcy = b1 + 0.5f * h + (d1 * 0.1f) * h;
            float pw  = __expf(d2 * 0.2f) * w;
            float ph  = __expf(d3 * 0.2f) * h;
            X1[j] = pcx - 0.5f * pw;  X4[j] = pcx + 0.5f * pw;
            Y1[j] = pcy - 0.5f * ph;  Y4[j] = pcy + 0.5f * ph;
            float pal = atanf(d4) + b4;
            PX[j] = pcx; PY[j] = pcy;
            SA[j] = __sinf(pal); CA[j] = __cosf(pal);
        }
        size_t rs = (size_t)N;
        *(h4v*)(V + (size_t)(0*8 + b) * rs + c) =
            (h4v){(_Float16)X1[0],(_Float16)X1[1],(_Float16)X1[2],(_Float16)X1[3]};
        *(h4v*)(V + (size_t)(1*8 + b) * rs + c) =
            (h4v){(_Float16)X4[0],(_Float16)X4[1],(_Float16)X4[2],(_Float16)X4[3]};
        *(h4v*)(V + (size_t)(2*8 + b) * rs + c) =
            (h4v){(_Float16)Y1[0],(_Float16)Y1[1],(_Float16)Y1[2],(_Float16)Y1[3]};
        *(h4v*)(V + (size_t)(3*8 + b) * rs + c) =
            (h4v){(_Float16)Y4[0],(_Float16)Y4[1],(_Float16)Y4[2],(_Float16)Y4[3]};
        h8v ctrA = {(_Float16)PX[0],(_Float16)PY[0],(_Float16)CA[0],(_Float16)SA[0],
                    (_Float16)PX[1],(_Float16)PY[1],(_Float16)CA[1],(_Float16)SA[1]};
        h8v ctrB = {(_Float16)PX[2],(_Float16)PY[2],(_Float16)CA[2],(_Float16)SA[2],
                    (_Float16)PX[3],(_Float16)PY[3],(_Float16)CA[3],(_Float16)SA[3]};
        *(h8v*)(CTR + (size_t)i0 * 4)     = ctrA;
        *(h8v*)(CTR + (size_t)i0 * 4 + 8) = ctrB;
    } else {
#pragma unroll 1
        for (int j = 0; j < 4; ++j) {
            int i = i0 + j;
            if (i >= total) break;
            int bb = i / N, cc = i - bb * N;
            const float* bx = boxes  + (size_t)i * 5;
            const float* dl = deltas + (size_t)i * 5;
            float b0=bx[0],b1=bx[1],b2=bx[2],b3=bx[3],b4=bx[4];
            float d0=dl[0],d1=dl[1],d2=dl[2],d3=dl[3],d4=dl[4];
            float w = b2-b0, h = b3-b1;
            float pcx = b0 + 0.5f*w + (d0*0.1f)*w;
            float pcy = b1 + 0.5f*h + (d1*0.1f)*h;
            float pw = __expf(d2*0.2f)*w, ph = __expf(d3*0.2f)*h;
            size_t rs = (size_t)N;
            V[(size_t)(0*8+bb)*rs + cc] = (_Float16)(pcx - 0.5f*pw);
            V[(size_t)(1*8+bb)*rs + cc] = (_Float16)(pcx + 0.5f*pw);
            V[(size_t)(2*8+bb)*rs + cc] = (_Float16)(pcy - 0.5f*ph);
            V[(size_t)(3*8+bb)*rs + cc] = (_Float16)(pcy + 0.5f*ph);
            float pal = atanf(d4) + b4;
            CTR[(size_t)i*4 + 0] = (_Float16)pcx;
            CTR[(size_t)i*4 + 1] = (_Float16)pcy;
            CTR[(size_t)i*4 + 2] = (_Float16)__cosf(pal);
            CTR[(size_t)i*4 + 3] = (_Float16)__sinf(pal);
        }
    }
}

__global__ __launch_bounds__(256) void bbox_phase2(
    const _Float16* __restrict__ V, const _Float16* __restrict__ CTR,
    float* __restrict__ out, int N, int total)
{
    int t = blockIdx.x * blockDim.x + threadIdx.x;
    int i0 = t * 2;
    if (i0 >= total) return;

    int f = i0 * 12;                 // < 24e6, fits int
    int r = f / N;
    int c = f - r * N;
    bool pair = (i0 + 1 < total);

    float P[24];
    bool fast = pair && (c + 23 < N) && ((c & 7) == 0);
    if (fast) {
        if (r < 64) {
            int k = r >> 3, bb = r & 7;
            int v = (k < 4) ? (k >> 1) : (2 + (k & 1));
            const h8v* wp = (const h8v*)(V + (size_t)(v*8 + bb) * N + c);
            h8v a = wp[0], d = wp[1], e = wp[2];
#pragma unroll
            for (int j = 0; j < 8; ++j) {
                P[j]      = (float)a[j];
                P[8 + j]  = (float)d[j];
                P[16 + j] = (float)e[j];
            }
        } else {
#pragma unroll
            for (int j = 0; j < 24; ++j) P[j] = 1.0f;
        }
    } else {
#pragma unroll 1
        for (int j = 0; j < 24; ++j) {
            if (!pair && j >= 12) { P[j] = 1.0f; continue; }
            int ff = f + j;
            int rt = ff / N;
            int ct = ff - rt * N;
            if (rt >= 64) { P[j] = 1.0f; }
            else {
                int k = rt >> 3, bb = rt & 7;
                int v = (k < 4) ? (k >> 1) : (2 + (k & 1));
                P[j] = (float)V[(size_t)(v*8 + bb) * N + ct];
            }
        }
    }

    float pcx[2], pcy[2], cav[2], sav[2];
    if (pair) {
        h8v cc = *(const h8v*)(CTR + (size_t)i0 * 4);
        pcx[0]=(float)cc[0]; pcy[0]=(float)cc[1]; cav[0]=(float)cc[2]; sav[0]=(float)cc[3];
        pcx[1]=(float)cc[4]; pcy[1]=(float)cc[5]; cav[1]=(float)cc[6]; sav[1]=(float)cc[7];
    } else {
        pcx[0]=(float)CTR[(size_t)i0*4+0]; pcy[0]=(float)CTR[(size_t)i0*4+1];
        cav[0]=(float)CTR[(size_t)i0*4+2]; sav[0]=(float)CTR[(size_t)i0*4+3];
        pcx[1]=0.f; pcy[1]=0.f; cav[1]=1.f; sav[1]=0.f;
    }

#pragma unroll
    for (int q = 0; q < 2; ++q) {
        if (q && !pair) break;
        float r0o[4], r1o[4];
#pragma unroll
        for (int j = 0; j < 4; ++j) {
            float p0 = P[q*12 + j], p1 = P[q*12 + 4 + j], p2 = P[q*12 + 8 + j];
            float u0 = p0 - pcx[q] * p2;     // Tinv @ P
            float u1 = p1 - pcy[q] * p2;
            float v0 = cav[q] * u0 - sav[q] * u1; // R @ ...
            float v1 = sav[q] * u0 + cav[q] * u1;
            r0o[j] = v0 + pcx[q] * p2;       // T @ ...
            r1o[j] = v1 + pcy[q] * p2;
        }
        f4v* op = (f4v*)(out + (size_t)(i0 + q) * 8);
        op[0] = (f4v){r0o[0], r1o[0], r0o[1], r1o[1]};
        op[1] = (f4v){r0o[2], r1o[2], r0o[3], r1o[3]};
    }
}

// ---- fallback (fused, no workspace) ----
__global__ __launch_bounds__(256) void bbox_fused_fallback(
    const float* __restrict__ boxes, const float* __restrict__ deltas,
    float* __restrict__ out, int N, int total)
{
    int idx = blockIdx.x * blockDim.x + threadIdx.x;
    if (idx >= total) return;
    int bp = idx / N;
    int n  = idx - bp * N;
    const float* bx = boxes  + (size_t)idx * 5;
    const float* dl = deltas + (size_t)idx * 5;
    float b0=bx[0],b1=bx[1],b2=bx[2],b3=bx[3],b4=bx[4];
    float d0=dl[0],d1=dl[1],d4=dl[4];
    float w=b2-b0, h=b3-b1;
    float pcx = b0+0.5f*w+(d0*0.1f)*w;
    float pcy = b1+0.5f*h+(d1*0.1f)*h;
    float pal = atanf(d4)+b4;
    float sa = __sinf(pal), ca = __cosf(pal);
    int m0 = n*12, q = m0/N, c0 = m0-q*N, r0 = bp*12+q;
    float P[12];
#pragma unroll
    for (int t = 0; t < 12; ++t) {
        int c = c0+t, r = r0;
        if (c >= N) { c -= N; r += 1; }
        float v;
        if (r >= 64) v = 1.0f;
        else {
            int k = r>>3, b = r&7;
            size_t base = ((size_t)b*N + c)*5;
            int a = (k<4)?0:1;
            float lo = boxes[base+a], hi = boxes[base+a+2];
            float dc = deltas[base+a], dd = deltas[base+a+2];
            float ww = hi-lo;
            float pc = lo+0.5f*ww+(dc*0.1f)*ww;
            float pwv = __expf(dd*0.2f)*ww;
            float s = ((0xAC>>k)&1)?0.5f:-0.5f;
            v = pc + s*pwv;
        }
        P[t] = v;
    }
    float r0o[4], r1o[4];
#pragma unroll
    for (int j = 0; j < 4; ++j) {
        float p0=P[j], p1=P[4+j], p2=P[8+j];
        float u0=p0-pcx*p2, u1=p1-pcy*p2;
        float v0=ca*u0-sa*u1, v1=sa*u0+ca*u1;
        r0o[j]=v0+pcx*p2; r1o[j]=v1+pcy*p2;
    }
    float4* op = (float4*)(out + (size_t)idx*8);
    op[0] = make_float4(r0o[0],r1o[0],r0o[1],r1o[1]);
    op[1] = make_float4(r0o[2],r1o[2],r0o[3],r1o[3]);
}

extern "C" void kernel_launch(void* const* d_in, const int* in_sizes, int n_in,
                              void* d_out, int out_size, void* d_ws, size_t ws_size,
                              hipStream_t stream) {
    const float* boxes  = (const float*)d_in[0];
    const float* deltas = (const float*)d_in[1];
    float* out = (float*)d_out;

    int total = in_sizes[0] / 5;     // B * N
    int N = total / 8;               // B == 8
    int threads = 256;

    size_t vBytes   = (size_t)32 * N * sizeof(_Float16);      // 16 MB
    size_t ctrBytes = (size_t)total * 4 * sizeof(_Float16);   // 16 MB
    // keep CTR 16B-aligned
    vBytes = (vBytes + 15) & ~(size_t)15;

    if (ws_size >= vBytes + ctrBytes) {
        _Float16* V   = (_Float16*)d_ws;
        _Float16* CTR = (_Float16*)((char*)d_ws + vBytes);
        int t1 = (total + 3) / 4;
        int blocks1 = (t1 + threads - 1) / threads;
        int t2 = (total + 1) / 2;
        int blocks2 = (t2 + threads - 1) / threads;
        bbox_phase1<<<blocks1, threads, 0, stream>>>(boxes, deltas, V, CTR, N, total);
        bbox_phase2<<<blocks2, threads, 0, stream>>>(V, CTR, out, N, total);
    } else {
        int blocks = (total + threads - 1) / threads;
        bbox_fused_fallback<<<blocks, threads, 0, stream>>>(boxes, deltas, out, N, total);
    }
}